// Round 11
// baseline (266.077 us; speedup 1.0000x reference)
//
#include <hip/hip_runtime.h>
#include <hip/hip_bf16.h>
#include <stdint.h>

namespace {

constexpr int IDIM   = 512;
constexpr int ODIM   = 512;
constexpr int KTOT   = 32768;            // 2 * IDIM * 32
constexpr int BM = 128, BN = 128, BK = 64;
constexpr int SPLITK = 8;
constexpr int KCHUNK = KTOT / SPLITK;    // 4096
constexpr int NSTEP  = KCHUNK / BK;      // 64

typedef short    bf16x8 __attribute__((ext_vector_type(8)));
typedef float    f32x4  __attribute__((ext_vector_type(4)));
typedef float    f32x2  __attribute__((ext_vector_type(2)));
typedef uint32_t u32x4  __attribute__((ext_vector_type(4)));

__device__ __forceinline__ uint32_t f2bf1(float f) {
  union { float f; uint32_t u; } v; v.f = f;
  return (v.u + 0x7fffu + ((v.u >> 16) & 1u)) >> 16;   // RTNE
}
__device__ __forceinline__ uint32_t pk2(float lo, float hi) {
  return f2bf1(lo) | (f2bf1(hi) << 16);
}
// fast pack: round-half-up (+0x8000) then v_perm_b32 grabs the two high halves.
__device__ __forceinline__ uint32_t pk2f(float lo, float hi) {
  union { float f; uint32_t u; } a, b; a.f = lo; b.f = hi;
  return __builtin_amdgcn_perm(b.u + 0x8000u, a.u + 0x8000u, 0x07060302u);
}

#define WAIT_LGKM0   asm volatile("s_waitcnt lgkmcnt(0)" ::: "memory")
#define WAIT_VM0     asm volatile("s_waitcnt vmcnt(0)" ::: "memory")
#define FENCE        asm volatile("" ::: "memory")

// ---------------- register-transpose convert: fc f32 [32768][512] -> wt bf16 [512][32768]
// (R6-verified, ~40 us)
__global__ __launch_bounds__(256) void transpose_convert_kernel(const float* __restrict__ fc,
                                                                uint16_t* __restrict__ wt) {
  const int t = threadIdx.x, lane = t & 63, wave = t >> 6;
  const int bid = blockIdx.x;
  const int ot = bid & 3;                  // 4 o-tiles of 128
  const int kt = bid >> 2;                 // 256 k-tiles of 128
  const int o0 = ot * 128 + lane * 2;
  const int kb = kt * 128 + wave * 32;     // wave covers 32 k
  const float* src = fc + (size_t)kb * ODIM + o0;
  uint32_t w0[16], w1[16];
#pragma unroll
  for (int p = 0; p < 16; ++p) {
    f32x2 a = *(const f32x2*)(src + (size_t)(2 * p) * ODIM);
    f32x2 b = *(const f32x2*)(src + (size_t)(2 * p + 1) * ODIM);
    w0[p] = pk2(a.x, b.x);
    w1[p] = pk2(a.y, b.y);
  }
  uint16_t* dst0 = wt + (size_t)o0 * KTOT + kb;
  uint16_t* dst1 = dst0 + KTOT;
#pragma unroll
  for (int c = 0; c < 4; ++c) {
    *(u32x4*)(dst0 + c * 8) = *(const u32x4*)&w0[c * 4];
    *(u32x4*)(dst1 + c * 8) = *(const u32x4*)&w1[c * 4];
  }
}

// ---------------- out[b][o] = bias[o]
__global__ __launch_bounds__(256) void init_bias_kernel(const float* __restrict__ bias,
                                                        float* __restrict__ out) {
  int i = blockIdx.x * 256 + threadIdx.x;
  ((f32x4*)out)[i] = ((const f32x4*)bias)[i & 127];
}

// ---------------- fused trig GEMM: A in LDS (shared trig, R7-verified path),
// B-fragments global->register double-buffered (no W LDS, no DMA).
__global__ __launch_bounds__(256, 2) void fkan_gemm_kernel(const float* __restrict__ x,
                                                           const uint16_t* __restrict__ wt,
                                                           float* __restrict__ out) {
  __shared__ char lds[32768];   // A dbuf only, 16 KB each

  const int t    = threadIdx.x;
  const int lane = t & 63;
  const int wave = t >> 6;
  const int lid  = lane & 15;
  const int hb   = lane >> 4;

  // XCD-aware swizzle (512 % 8 == 0 -> bijective)
  int bid = blockIdx.x;
  int swz = (bid & 7) * 64 + (bid >> 3);
  const int bm = swz & 15;
  const int bn = (swz >> 4) & 3;
  const int bz = swz >> 6;

  const int row0  = bm * BM;
  const int col0  = bn * BN;
  const int kc0   = bz * KCHUNK;
  const int sflag = bz >> 2;              // 0: cos half, 1: sin half
  const int ibase = (bz & 3) * 128;

  // ---- A generation mapping (R7-verified): thread -> (row gr, i-offset ioff)
  const int gr   = t & 127;
  const int ioff = t >> 7;
  const float* xp = x + (size_t)(row0 + gr) * IDIM + ibase + ioff;
  int awoff[4];
#pragma unroll
  for (int j = 0; j < 4; ++j)
    awoff[j] = gr * 128 + (((ioff * 4 + j) ^ (gr & 7)) << 4);

  // ---- A fragment read offsets (R7-verified swizzled path)
  const int wm = wave >> 1, wn = wave & 1;
  int arow[4], ar7[4];
#pragma unroll
  for (int m = 0; m < 4; ++m) {
    int rr = wm * 64 + m * 16 + lid;
    arow[m] = rr * 128; ar7[m] = rr & 7;
  }

  // ---- B fragment global base pointers: lane needs wt[col][k-window], 16B each.
  // col = col0 + wn*64 + n*16 + lid; k = kc0 + st*64 + ks*32 + hb*8.
  // Wave pattern per load: 16 cols x 64B contiguous lines -> fully coalesced.
  const uint16_t* bp[4];
#pragma unroll
  for (int n = 0; n < 4; ++n)
    bp[n] = wt + (size_t)(col0 + wn * 64 + n * 16 + lid) * KTOT + kc0 + hb * 8;

  f32x4 acc[4][4] = {};

  auto loadB = [&](bf16x8 (&d)[8], int st) {
#pragma unroll
    for (int ks = 0; ks < 2; ++ks)
#pragma unroll
      for (int n = 0; n < 4; ++n)
        d[ks * 4 + n] = *(const bf16x8*)(bp[n] + st * BK + ks * 32);
  };

  // genA (R7-verified): dual stride-2 Chebyshev chains via cos/sin 2x.
  auto genA = [&](int abuf, float ang) {
    float s1, c1;
    __sincosf(ang, &s1, &c1);
    const float c2 = 2.f * c1 * c1 - 1.f;
    const float s2 = 2.f * s1 * c1;
    const float k2 = 2.f * c2;
    float po  = sflag ? s1   : c1;
    float pe  = sflag ? s2   : c2;
    float pom = sflag ? -s1  : c1;
    float pem = sflag ? 0.f  : 1.f;
    char* ab = lds + abuf * 16384;
#pragma unroll
    for (int grp = 0; grp < 4; ++grp) {
      u32x4 w;
#pragma unroll
      for (int u = 0; u < 4; ++u) {
        w[u] = pk2f(po, pe);
        float no = k2 * po - pom; pom = po; po = no;
        float ne = k2 * pe - pem; pem = pe; pe = ne;
      }
      *(u32x4*)(ab + awoff[grp]) = w;
    }
  };

  auto compute = [&](int par, const bf16x8 (&bfr)[8]) {
    const char* ab = lds + par * 16384;
#pragma unroll
    for (int ks = 0; ks < 2; ++ks) {
      const int ksb = ks * 4 + hb;
      bf16x8 af[4];
#pragma unroll
      for (int m = 0; m < 4; ++m)
        af[m] = *(const bf16x8*)(ab + arow[m] + ((ksb ^ ar7[m]) << 4));
#pragma unroll
      for (int m = 0; m < 4; ++m)
#pragma unroll
        for (int n = 0; n < 4; ++n)
          acc[m][n] = __builtin_amdgcn_mfma_f32_16x16x32_bf16(af[m], bfr[ks * 4 + n], acc[m][n], 0, 0, 0);
    }
  };

  bf16x8 bA[8], bB[8];

  // ---- prologue: B(0) + A(0)
  float angCur  = xp[0];
  float angNext = xp[2];
  loadB(bA, 0);
  genA(0, angCur);
  WAIT_VM0;                  // B(0) regs full
  WAIT_LGKM0;                // own A writes drained
  __builtin_amdgcn_s_barrier();
  FENCE;

  int par = 0;
  auto iter = [&](int st, const bf16x8 (&bC)[8], bf16x8 (&bN)[8]) {
    if (st + 1 < NSTEP) {
      loadB(bN, st + 1);     // 8 coalesced 16B loads; land under genA+compute
      float a = angNext;
      if (st + 2 < NSTEP) angNext = xp[2 * (st + 2)];
      genA(par ^ 1, a);
    }
    compute(par, bC);
    if (st + 1 < NSTEP) {
      WAIT_VM0;              // B(st+1) + angle loads complete
      WAIT_LGKM0;            // A(st+1) ds-writes visible past barrier
      __builtin_amdgcn_s_barrier();
      FENCE;
    }
    par ^= 1;
  };

#pragma unroll 1
  for (int st2 = 0; st2 < NSTEP; st2 += 2) {   // 2x unroll: static B-buf names
    iter(st2,     bA, bB);
    iter(st2 + 1, bB, bA);
  }

  // ---- epilogue: split-K reduce via atomics (out pre-initialized with bias)
#pragma unroll
  for (int m = 0; m < 4; ++m) {
#pragma unroll
    for (int n = 0; n < 4; ++n) {
      int rr = row0 + wm * 64 + m * 16 + ((lane >> 4) << 2);
      int cc = col0 + wn * 64 + n * 16 + lid;
#pragma unroll
      for (int j = 0; j < 4; ++j)
        atomicAdd(out + (size_t)(rr + j) * ODIM + cc, acc[m][n][j]);
    }
  }
}

}  // namespace

extern "C" void kernel_launch(void* const* d_in, const int* in_sizes, int n_in,
                              void* d_out, int out_size, void* d_ws, size_t ws_size,
                              hipStream_t stream) {
  const float* x    = (const float*)d_in[0];
  const float* fc   = (const float*)d_in[1];   // [2,512,32,512] == [32768][512]
  const float* bias = (const float*)d_in[2];
  float*    out = (float*)d_out;
  uint16_t* wt  = (uint16_t*)d_ws;             // 33.5 MB bf16, o-major

  transpose_convert_kernel<<<1024, 256, 0, stream>>>(fc, wt);
  init_bias_kernel<<<1024, 256, 0, stream>>>(bias, out);
  fkan_gemm_kernel<<<512, 256, 0, stream>>>(x, wt, out);
}